// Round 1
// baseline (316.533 us; speedup 1.0000x reference)
//
#include <hip/hip_runtime.h>
#include <hip/hip_bf16.h>

typedef short s16x8 __attribute__((ext_vector_type(8)));
typedef float f32x4 __attribute__((ext_vector_type(4)));
typedef float f32x16 __attribute__((ext_vector_type(16)));

// ---------- helpers ----------
__device__ __forceinline__ unsigned short f2bf(float f) {
  unsigned u = __float_as_uint(f);
  u += 0x7fffu + ((u >> 16) & 1u);   // round-to-nearest-even
  return (unsigned short)(u >> 16);
}

__device__ __forceinline__ void gload16(const void* g, void* l) {
  __builtin_amdgcn_global_load_lds(
      (const __attribute__((address_space(1))) unsigned int*)g,
      (__attribute__((address_space(3))) unsigned int*)l,
      16, 0, 0);
}

// ---------- kernel 1: blockwise FWHT of W rows, scale 1/32, cast bf16 ----------
__global__ void __launch_bounds__(256) k_had_w(const float* __restrict__ W,
                                               unsigned short* __restrict__ Wh) {
  __shared__ float s[1024];
  const size_t base = (size_t)blockIdx.x * 1024;
  const int t = threadIdx.x;

  float4 v = reinterpret_cast<const float4*>(W + base)[t];
  s[4 * t + 0] = v.x;
  s[4 * t + 1] = v.y;
  s[4 * t + 2] = v.z;
  s[4 * t + 3] = v.w;

#pragma unroll
  for (int h = 1; h < 1024; h <<= 1) {
    __syncthreads();
#pragma unroll
    for (int pp = 0; pp < 2; ++pp) {
      int p = t + pp * 256;
      int i = ((p / h) * (h << 1)) + (p % h);
      float a = s[i], b = s[i + h];
      s[i] = a + b;
      s[i + h] = a - b;
    }
  }
  __syncthreads();

  const float sc = 0.03125f;  // 1/sqrt(1024)
  ushort4 o;
  o.x = f2bf(s[4 * t + 0] * sc);
  o.y = f2bf(s[4 * t + 1] * sc);
  o.z = f2bf(s[4 * t + 2] * sc);
  o.w = f2bf(s[4 * t + 3] * sc);
  reinterpret_cast<ushort4*>(Wh + base)[t] = o;
}

// ---------- kernel 2: x f32 -> bf16 ----------
__global__ void __launch_bounds__(256) k_cast(const float* __restrict__ x,
                                              unsigned short* __restrict__ xb,
                                              long n4) {
  long i = (long)blockIdx.x * 256 + threadIdx.x;
  const long stride = (long)gridDim.x * 256;
  for (; i < n4; i += stride) {
    float4 v = reinterpret_cast<const float4*>(x)[i];
    ushort4 o;
    o.x = f2bf(v.x);
    o.y = f2bf(v.y);
    o.z = f2bf(v.z);
    o.w = f2bf(v.w);
    reinterpret_cast<ushort4*>(xb)[i] = o;
  }
}

// ---------- kernel 3: 256x256 bf16 GEMM, R4 schedule, 32x32x16 MFMA ----------
// A: [M][K] bf16, B: [N][K] bf16, C: [M][N] f32.
// 8 waves (2M x 4N), BK=64. LDS: A 3x32KB (triple buffer) + B 2x32KB = 160KB.
// Same R4 schedule / staging / chunk-XOR swizzle as the 16x16 version; only the
// MFMA shape changed: per wave 4x2 fragments of 32x32, 4 k-slices of 16.
// A/B operand: lane l holds row/col (l&31), k = 8*(l>>5)+e  (one 16B chunk).
// C/D layout (32x32): col = lane&31, row = (reg&3)+8*(reg>>2)+4*(lane>>5)  [m74/m101]

#define STAGE_HALF(gbase, halfRow, koff, ldsDst)                             \
  do {                                                                       \
    gload16(gbase + (size_t)(halfRow)*K + (koff), (ldsDst) + tid * 16);      \
    gload16(gbase + (size_t)((halfRow) + 64)*K + (koff),                     \
            (ldsDst) + 8192 + tid * 16);                                     \
  } while (0)

// A fragments for one M-half (msel): 2 frags x 4 k-slices = 8 x ds_read_b128
#define RD_A(bufp, dst, msel)                                                \
  do { _Pragma("unroll")                                                     \
    for (int i = 0; i < 2; ++i) { _Pragma("unroll")                          \
      for (int kk = 0; kk < 4; ++kk) {                                       \
        dst[i][kk] = *(const s16x8*)((bufp) + abase + (msel)*8192 +          \
                                     i * 4096 + cs[kk]);                     \
      } } } while (0)

// B fragment for one N-half (nsel): 1 frag x 4 k-slices = 4 x ds_read_b128
#define RD_B(bufp, dst, nsel)                                                \
  do { _Pragma("unroll")                                                     \
    for (int kk = 0; kk < 4; ++kk) {                                         \
      dst[kk] = *(const s16x8*)((bufp) + bbase + (nsel)*4096 + cs[kk]);      \
    } } while (0)

#define MFMA_Q(msel, nsel, AF, BF)                                           \
  do {                                                                       \
    __builtin_amdgcn_s_setprio(1);                                           \
    _Pragma("unroll")                                                        \
    for (int kk = 0; kk < 4; ++kk) {                                         \
      _Pragma("unroll")                                                      \
      for (int i = 0; i < 2; ++i) {                                          \
        acc[(msel)*2 + i][nsel] =                                            \
          __builtin_amdgcn_mfma_f32_32x32x16_bf16(                           \
            AF[i][kk], BF[kk], acc[(msel)*2 + i][nsel], 0, 0, 0);            \
      }                                                                      \
    }                                                                        \
    __builtin_amdgcn_s_setprio(0);                                           \
  } while (0)

#define BAR() __builtin_amdgcn_s_barrier()

__global__ void __launch_bounds__(512, 2) k_gemm256(
    const unsigned short* __restrict__ A, const unsigned short* __restrict__ B,
    const float* __restrict__ bias, float* __restrict__ C,
    int M, int N, int K) {
  __shared__ char LDS[163840];   // A: 3 x 32KB @ 0/32768/65536; B: 2 x 32KB @ 98304/131072

  const int tid = threadIdx.x;
  const int lane = tid & 63;
  const int wid = tid >> 6;
  const int wm = wid >> 2;     // 0..1
  const int wn = wid & 3;      // 0..3
  const int r31 = lane & 31;   // row/col within 32x32 fragment
  const int h = lane >> 5;     // k-half selector

  // XCD-aware bijective swizzle (grid = 512, divisible by 8)
  const int nbn = N >> 8;
  const int cpx = gridDim.x >> 3;
  const int swz = (blockIdx.x & 7) * cpx + (blockIdx.x >> 3);
  const int bm = swz / nbn, bn = swz % nbn;

  // ---- staging addressing (linear LDS dest, pre-swizzled global source) ----
  const int r0 = tid >> 3;
  const int ck = (tid & 7) ^ (r0 & 7);
  const unsigned short* gAbase = A + (size_t)(bm * 256 + r0) * K + ck * 8;
  const unsigned short* gBbase = B + (size_t)(bn * 256 + r0) * K + ck * 8;

  // ---- fragment read offsets (0-conflict chunk-XOR pattern) ----
  // chunk for k-slice kk: global chunk (2*kk + h), XOR'd with (row&7)
  int cs[4];
#pragma unroll
  for (int kk = 0; kk < 4; ++kk)
    cs[kk] = (((kk * 2 + h) ^ (r31 & 7)) << 4);
  const int abase = wm * 16384 + r31 * 128;
  const int bbase = (wn >> 1) * 16384 + (wn & 1) * 8192 + r31 * 128;

  f32x16 acc[4][2];
#pragma unroll
  for (int m = 0; m < 4; ++m)
#pragma unroll
    for (int n = 0; n < 2; ++n)
#pragma unroll
      for (int j = 0; j < 16; ++j) acc[m][n][j] = 0.f;

  s16x8 af0[2][4], af1[2][4], bf0[4], bf1[4];

  // ---- prologue: A(0)->bufA0, B(0)->bufB0, A(1)->bufA1, B(1)->bufB1 ----
  STAGE_HALF(gAbase, 0,   0, LDS);                    // A(0) rows 0-127
  STAGE_HALF(gAbase, 128, 0, LDS + 16384);            // A(0) rows 128-255
  STAGE_HALF(gBbase, 0,   0, LDS + 98304);            // B(0) rows 0-127
  STAGE_HALF(gBbase, 128, 0, LDS + 98304 + 16384);    // B(0) rows 128-255
  STAGE_HALF(gAbase, 0,   64, LDS + 32768);           // A(1)
  STAGE_HALF(gAbase, 128, 64, LDS + 32768 + 16384);
  STAGE_HALF(gBbase, 0,   64, LDS + 131072);          // B(1)
  STAGE_HALF(gBbase, 128, 64, LDS + 131072 + 16384);
  asm volatile("s_waitcnt vmcnt(8)" ::: "memory");    // A(0),B(0) landed
  BAR();
  RD_A(LDS, af0, 0);
  RD_B(LDS + 98304, bf0, 0);

  const int nt = K >> 6;  // 64
  int am = 0, an = 1, an2 = 2;   // A buffer rotation (t, t+1, t+2) mod 3
  for (int t = 0; t < nt; ++t) {
    const char* bA  = LDS + am * 32768;
    const char* bAn = LDS + an * 32768;
    char*       bAs = LDS + an2 * 32768;                    // A(t+2) dest
    const char* bB  = LDS + 98304 + ((t & 1) << 15);
    const char* bBn = LDS + 98304 + (((t + 1) & 1) << 15);
    char*       bBs = (char*)bB;                            // B(t+2) dest (same parity)
    const int koff2 = (t + 2) << 6;

    // ---- ph1: reads bf1+af1 (12); stage A(t+2) rows 0-127; BAR; q(0,0)
    RD_B(bB, bf1, 1);
    RD_A(bA, af1, 1);
    if (t + 2 < nt) STAGE_HALF(gAbase, 0, koff2, bAs);
    BAR();
    MFMA_Q(0, 0, af0, bf0);

    // ---- ph2: stage A(t+2) rows 128-255; BAR; q(0,1)
    if (t + 2 < nt) STAGE_HALF(gAbase, 128, koff2, bAs + 16384);
    BAR();
    MFMA_Q(0, 1, af0, bf1);

    // ---- ph3: stage B(t+2) rows 0-127 (bf0/bf1(t) reads drained >=1 BAR ago);
    //      BAR; q(1,0)
    if (t + 2 < nt) STAGE_HALF(gBbase, 0, koff2, bBs);
    BAR();
    MFMA_Q(1, 0, af1, bf0);

    // ---- ph4: stage B(t+2) rows 128-255; counted vmcnt; BAR;
    //      next-tile af0/bf0 reads; q(1,1)
    if (t + 2 < nt) STAGE_HALF(gBbase, 128, koff2, bBs + 16384);
    if (t < nt - 2) {
      asm volatile("s_waitcnt vmcnt(8)" ::: "memory");  // A(t+1),B(t+1) landed
    } else if (t == nt - 2) {
      asm volatile("s_waitcnt vmcnt(0)" ::: "memory");  // tail drain
    }
    BAR();
    if (t + 1 < nt) {
      RD_A(bAn, af0, 0);
      RD_B(bBn, bf0, 0);
    }
    MFMA_Q(1, 1, af1, bf1);

    // rotate A buffers
    const int tmp = am;
    am = an; an = an2; an2 = tmp;
  }

  // ---- epilogue: C = acc + bias ----
  // C/D layout (32x32): col = lane&31, row = (reg&3)+8*(reg>>2)+4*(lane>>5)
  const int row0 = bm * 256 + wm * 128;
  const int col0 = bn * 256 + wn * 64;
  float bv[2];
#pragma unroll
  for (int nf = 0; nf < 2; ++nf) bv[nf] = bias[col0 + nf * 32 + r31];

#pragma unroll
  for (int mf = 0; mf < 4; ++mf) {
#pragma unroll
    for (int nf = 0; nf < 2; ++nf) {
#pragma unroll
      for (int reg = 0; reg < 16; ++reg) {
        const int r = row0 + mf * 32 + (reg & 3) + ((reg >> 2) << 3) + (h << 2);
        const int c = col0 + nf * 32 + r31;
        C[(size_t)r * N + c] = acc[mf][nf][reg] + bv[nf];
      }
    }
  }
}

// ---------- launcher ----------
extern "C" void kernel_launch(void* const* d_in, const int* in_sizes, int n_in,
                              void* d_out, int out_size, void* d_ws, size_t ws_size,
                              hipStream_t stream) {
  const float* x = (const float*)d_in[0];
  const float* W = (const float*)d_in[1];
  const float* b = (const float*)d_in[2];
  float* out = (float*)d_out;

  const int N = in_sizes[2];                 // 4096 (D_OUT)
  const int K = in_sizes[1] / N;             // 4096 (D_IN)
  const int M = in_sizes[0] / K;             // 8192 (B*S)

  unsigned short* Xb = (unsigned short*)d_ws;              // M*K bf16
  unsigned short* Wh = Xb + (size_t)M * K;                 // N*K bf16

  const int nblk = (int)(((size_t)N * K) / 1024);
  k_had_w<<<nblk, 256, 0, stream>>>(W, Wh);

  const long n4 = ((long)M * K) / 4;
  k_cast<<<4096, 256, 0, stream>>>(x, Xb, n4);

  const int grid = (M / 256) * (N / 256);    // 512
  k_gemm256<<<grid, 512, 0, stream>>>(Xb, Wh, b, out, M, N, K);
}